// Round 1
// baseline (45.969 us; speedup 1.0000x reference)
//
#include <hip/hip_runtime.h>

// ResiduePose: coords[b,l,a,i] = R(q_norm)[i,:] · P[a,:] + (t[b,l,i] - mean_l t[b,:,i])
// B=32, L=65536. Memory-bound; deterministic 2-stage mean + fused main pass.

#define BB 32
#define LL 65536
#define PB 32          // partial-sum blocks per batch
#define MAIN_GRID 2048

// ---------------- stage 1: per-(batch, block) partial sums of translation ----------------
__global__ __launch_bounds__(256) void partial_sums_kernel(
    const float* __restrict__ trans, float* __restrict__ partials) {
    const int b = blockIdx.x / PB;
    const int p = blockIdx.x % PB;
    const float* base = trans + (size_t)b * LL * 3;

    float s0 = 0.f, s1 = 0.f, s2 = 0.f;
    const int start = p * (LL / PB);            // residue offset for this block
    constexpr int ITERS = LL / (PB * 256);      // = 8
#pragma unroll
    for (int k = 0; k < ITERS; ++k) {
        const int r = start + k * 256 + threadIdx.x;
        const float* pr = base + (size_t)r * 3;
        s0 += pr[0];
        s1 += pr[1];
        s2 += pr[2];
    }
    // wave(64) butterfly-free down-reduce
#pragma unroll
    for (int off = 32; off > 0; off >>= 1) {
        s0 += __shfl_down(s0, off);
        s1 += __shfl_down(s1, off);
        s2 += __shfl_down(s2, off);
    }
    __shared__ float red[4][3];
    const int wave = threadIdx.x >> 6;
    if ((threadIdx.x & 63) == 0) {
        red[wave][0] = s0; red[wave][1] = s1; red[wave][2] = s2;
    }
    __syncthreads();
    if (threadIdx.x == 0) {
        float a0 = 0.f, a1 = 0.f, a2 = 0.f;
#pragma unroll
        for (int w = 0; w < 4; ++w) { a0 += red[w][0]; a1 += red[w][1]; a2 += red[w][2]; }
        float* dst = partials + ((size_t)b * PB + p) * 3;
        dst[0] = a0; dst[1] = a1; dst[2] = a2;
    }
}

// ---------------- stage 2: reduce partials -> means (one tiny block) ----------------
__global__ __launch_bounds__(128) void finalize_means_kernel(
    const float* __restrict__ partials, float* __restrict__ means) {
    const int i = threadIdx.x;
    if (i < BB * 3) {
        const int b = i / 3, c = i % 3;
        float s = 0.f;
#pragma unroll
        for (int p = 0; p < PB; ++p) s += partials[((size_t)b * PB + p) * 3 + c];
        means[i] = s * (1.0f / (float)LL);
    }
}

// ---------------- main: quat -> R, rotate 4 idealized atoms, add centered t ----------------
__global__ __launch_bounds__(256) void pose_kernel(
    const float* __restrict__ trans, const float4* __restrict__ quat,
    const float* __restrict__ means, float4* __restrict__ out) {
    const int total = BB * LL;
    for (int idx = blockIdx.x * blockDim.x + threadIdx.x; idx < total;
         idx += gridDim.x * blockDim.x) {
        const int b = idx >> 16;   // L = 65536
        const float4 q4 = quat[idx];

        const float mx = means[b * 3 + 0];
        const float my = means[b * 3 + 1];
        const float mz = means[b * 3 + 2];
        const float* tp = trans + (size_t)idx * 3;
        const float tx = tp[0] - mx;
        const float ty = tp[1] - my;
        const float tz = tp[2] - mz;

        float r = q4.x, i = q4.y, j = q4.z, k = q4.w;
        const float inv = 1.0f / (sqrtf(r * r + i * i + j * j + k * k) + 1e-6f);
        r *= inv; i *= inv; j *= inv; k *= inv;

        const float R00 = 1.f - 2.f * (j * j + k * k);
        const float R01 = 2.f * (i * j - k * r);
        const float R02 = 2.f * (i * k + j * r);
        const float R10 = 2.f * (i * j + k * r);
        const float R11 = 1.f - 2.f * (i * i + k * k);
        const float R12 = 2.f * (j * k - i * r);
        const float R20 = 2.f * (i * k - j * r);
        const float R21 = 2.f * (j * k + i * r);
        const float R22 = 1.f - 2.f * (i * i + j * j);

        // idealized internal coords (N, CA=origin, C, CB)
        const float Nx = 1.460091f;
        const float Cx = -0.56431316f, Cy = 1.41695817f;
        const float Bx = -0.52426314f, By = -0.76611338f, Bz = 1.20561194f;

        const float N0 = R00 * Nx + tx, N1 = R10 * Nx + ty, N2 = R20 * Nx + tz;
        const float C0 = R00 * Cx + R01 * Cy + tx;
        const float C1 = R10 * Cx + R11 * Cy + ty;
        const float C2 = R20 * Cx + R21 * Cy + tz;
        const float B0 = R00 * Bx + R01 * By + R02 * Bz + tx;
        const float B1 = R10 * Bx + R11 * By + R12 * Bz + ty;
        const float B2 = R20 * Bx + R21 * By + R22 * Bz + tz;

        // output layout per residue: N(3) CA(3) C(3) CB(3) = 12 floats = 3 float4
        const size_t o = (size_t)idx * 3;
        out[o + 0] = make_float4(N0, N1, N2, tx);
        out[o + 1] = make_float4(ty, tz, C0, C1);
        out[o + 2] = make_float4(C2, B0, B1, B2);
    }
}

extern "C" void kernel_launch(void* const* d_in, const int* in_sizes, int n_in,
                              void* d_out, int out_size, void* d_ws, size_t ws_size,
                              hipStream_t stream) {
    const float* trans = (const float*)d_in[0];        // (B,L,3) f32
    const float4* quat = (const float4*)d_in[1];       // (B,L,4) f32
    float* out = (float*)d_out;                        // (B,L,4,3) f32

    float* partials = (float*)d_ws;                    // B*PB*3 floats
    float* means = partials + (size_t)BB * PB * 3;     // B*3 floats

    partial_sums_kernel<<<BB * PB, 256, 0, stream>>>(trans, partials);
    finalize_means_kernel<<<1, 128, 0, stream>>>(partials, means);
    pose_kernel<<<MAIN_GRID, 256, 0, stream>>>(trans, (const float4*)quat, means,
                                               (float4*)out);
}